// Round 8
// baseline (383.840 us; speedup 1.0000x reference)
//
#include <hip/hip_runtime.h>
#include <math.h>

// Problem constants
#define D_ELEMS 25088   // C*H*W = 512*7*7
#define D4      6272    // D_ELEMS / 4
#define N_MEM   2000
#define B_KEYS  32
#define PI_2F   1.570795f   // 3.14159 / 2, matches reference
#define EPSF    1e-8f
#define NSLICE  49          // k-slices for k_dots_mfma
#define KSLICE  512         // 25088 / 49
#define KSTEPS  16          // KSLICE / 32
#define RTILE   200         // n-rows per w/LDS tile in k_read (50 rows/wave)

using short8 = __attribute__((ext_vector_type(8))) short;   // 8 bf16 A/B frag
using short4v = __attribute__((ext_vector_type(4))) short;
using f32x4  = __attribute__((ext_vector_type(4))) float;   // C/D frag

// ws layout (floats):
//   keyb (bf16 keys, as shorts)   : [0, 401408)
//   dots_part [49][2000][32]      : [401408, 3537408)
//   mn2_part  [49][2000]          : [3537408, 3635408)
//   dots      [2000][32]          : [3635408, 3699408)
//   mn2       [2000]              : [3699408, 3701408)
//   knorm     [32]                : [3701408, 3701440)
//   w         [2000][32]          : [3701440, 3765440)   (16B aligned)
//   partial [ns][32][25088]       : [3765440, +ns*802816) (16B aligned)

__device__ inline short f2bf(float x) {   // fp32 -> bf16 RNE (inputs finite)
    union { float f; unsigned u; } v; v.f = x;
    unsigned r = v.u + 0x7fffu + ((v.u >> 16) & 1u);
    return (short)(r >> 16);
}

// Convert keys fp32 -> bf16. 802816 elems, 4 per thread, grid 784*256.
__global__ __launch_bounds__(256) void k_prep(const float* __restrict__ key,
                                              short* __restrict__ keyb) {
    const int i = blockIdx.x * 256 + threadIdx.x;   // float4 index
    const float4 f = ((const float4*)key)[i];
    short4v s; s[0] = f2bf(f.x); s[1] = f2bf(f.y); s[2] = f2bf(f.z); s[3] = f2bf(f.w);
    ((short4v*)keyb)[i] = s;
}

// knorm[b] = max(||key[b]||, eps). 32 blocks x 256 threads, shuffle reduce.
__global__ __launch_bounds__(256) void k_knorm(const float* __restrict__ key,
                                               float* __restrict__ knorm) {
    const int b   = blockIdx.x;
    const int tid = threadIdx.x;
    const float4* K4 = (const float4*)(key + (size_t)b * D_ELEMS);
    float ks = 0.f;
    for (int i = tid; i < D4; i += 256) {
        const float4 f = K4[i];
        ks += f.x * f.x + f.y * f.y + f.z * f.z + f.w * f.w;
    }
#pragma unroll
    for (int o = 1; o < 64; o <<= 1) ks += __shfl_xor(ks, o, 64);
    __shared__ float sred[4];
    if ((tid & 63) == 0) sred[tid >> 6] = ks;
    __syncthreads();
    if (tid == 0)
        knorm[b] = fmaxf(sqrtf(sred[0] + sred[1] + sred[2] + sred[3]), EPSF);
}

// dots_part[s][n][b] = sum_{k in slice s} key[b][k]*mem[n][k]  (bf16 MFMA)
// mn2_part[s][n]     = sum_{k in slice s} mem[n][k]^2          (fp32)
// grid: 125 n-tiles x 49 slices = 6125 blocks of 1 wave (R1-exact).
__global__ __launch_bounds__(64) void k_dots_mfma(const short* __restrict__ keyb,
                                                  const float* __restrict__ mem,
                                                  float* __restrict__ dots_part,
                                                  float* __restrict__ mn2_part) {
    const int nt   = blockIdx.x / NSLICE;     // 0..124
    const int s    = blockIdx.x % NSLICE;     // 0..48
    const int n0   = nt * 16;
    const int lane = threadIdx.x;             // 0..63
    const int quad = lane >> 4;
    const int l16  = lane & 15;
    const int k0   = s * KSLICE + quad * 8;   // this lane's k base (floats)

    const short* a0p = keyb + (size_t)l16 * D_ELEMS + k0;          // keys 0..15
    const short* a1p = keyb + (size_t)(16 + l16) * D_ELEMS + k0;   // keys 16..31
    const float4* bp = (const float4*)(mem + (size_t)(n0 + l16) * D_ELEMS + k0);

    f32x4 acc0 = {0.f, 0.f, 0.f, 0.f};
    f32x4 acc1 = {0.f, 0.f, 0.f, 0.f};
    float msq = 0.f;

    // depth-1 prefetch: loads for step t+1 issue before the cvt+mfma of t
    short8 a0 = *(const short8*)a0p;
    short8 a1 = *(const short8*)a1p;
    float4 f0 = bp[0], f1 = bp[1];

    for (int t = 0; t < KSTEPS; ++t) {
        const short8 a0c = a0, a1c = a1;
        const float4 f0c = f0, f1c = f1;
        if (t + 1 < KSTEPS) {                 // wave-uniform branch
            a0 = *(const short8*)(a0p + (t + 1) * 32);
            a1 = *(const short8*)(a1p + (t + 1) * 32);
            f0 = bp[(t + 1) * 8];
            f1 = bp[(t + 1) * 8 + 1];
        }
        msq += f0c.x * f0c.x + f0c.y * f0c.y + f0c.z * f0c.z + f0c.w * f0c.w
             + f1c.x * f1c.x + f1c.y * f1c.y + f1c.z * f1c.z + f1c.w * f1c.w;
        short8 b;
        b[0] = f2bf(f0c.x); b[1] = f2bf(f0c.y); b[2] = f2bf(f0c.z); b[3] = f2bf(f0c.w);
        b[4] = f2bf(f1c.x); b[5] = f2bf(f1c.y); b[6] = f2bf(f1c.z); b[7] = f2bf(f1c.w);
        acc0 = __builtin_amdgcn_mfma_f32_16x16x32_bf16(a0c, b, acc0, 0, 0, 0);
        acc1 = __builtin_amdgcn_mfma_f32_16x16x32_bf16(a1c, b, acc1, 0, 0, 0);
    }

    // D[row=quad*4+r][col=l16]; row = key index (per m-half), col = n index
    float* dp = dots_part + (size_t)(s * N_MEM + n0 + l16) * B_KEYS;
#pragma unroll
    for (int r = 0; r < 4; ++r) {
        dp[quad * 4 + r]      = acc0[r];
        dp[16 + quad * 4 + r] = acc1[r];
    }

    // reduce msq across the 4 quads of each n-row (lanes l16, l16+16, ...)
    msq += __shfl_xor(msq, 16, 64);
    msq += __shfl_xor(msq, 32, 64);
    if (lane < 16) mn2_part[s * N_MEM + n0 + lane] = msq;
}

// Collapse the 49 slice partials: dots[n][b], mn2[n]. Coalesced. grid 250.
__global__ __launch_bounds__(256) void k_reduce(const float* __restrict__ dots_part,
                                                const float* __restrict__ mn2_part,
                                                float* __restrict__ dots,
                                                float* __restrict__ mn2) {
    const int gid = blockIdx.x * 256 + threadIdx.x;   // 0..63999
    float ds = 0.f;
#pragma unroll
    for (int s = 0; s < NSLICE; ++s) ds += dots_part[s * (N_MEM * B_KEYS) + gid];
    dots[gid] = ds;
    if (gid < N_MEM) {
        float ms = 0.f;
#pragma unroll
        for (int s = 0; s < NSLICE; ++s) ms += mn2_part[s * N_MEM + gid];
        mn2[gid] = ms;
    }
}

// per-b: cos -> tan -> softmax over n -> w. knorm precomputed by k_knorm.
__global__ __launch_bounds__(512) void k_softmax(const float* __restrict__ knormArr,
                                                 const float* __restrict__ dots,
                                                 const float* __restrict__ mn2,
                                                 float* __restrict__ w) {
    const int b   = blockIdx.x;
    const int tid = threadIdx.x;
    __shared__ float sred[512];
    __shared__ float xbuf[N_MEM];
    const float knorm = knormArr[b];

    float mx = -1e30f;
    for (int n = tid; n < N_MEM; n += 512) {
        const float mn = fmaxf(sqrtf(mn2[n]), EPSF);
        const float x  = __tanf((dots[n * B_KEYS + b] / (knorm * mn)) * PI_2F);
        xbuf[n] = x;
        mx = fmaxf(mx, x);
    }
    sred[tid] = mx;
    __syncthreads();
    for (int o = 256; o; o >>= 1) {
        if (tid < o) sred[tid] = fmaxf(sred[tid], sred[tid + o]);
        __syncthreads();
    }
    mx = sred[0];
    __syncthreads();

    float sm = 0.f;
    for (int n = tid; n < N_MEM; n += 512) {   // cache exp in xbuf (own slots)
        const float e = __expf(xbuf[n] - mx);
        xbuf[n] = e;
        sm += e;
    }
    sred[tid] = sm;
    __syncthreads();
    for (int o = 256; o; o >>= 1) {
        if (tid < o) sred[tid] += sred[tid + o];
        __syncthreads();
    }
    const float inv = 1.f / sred[0];

    for (int n = tid; n < N_MEM; n += 512)
        w[n * B_KEYS + b] = xbuf[n] * inv;
}

// partial[s][b][d] = sum_{n in split s} w[n][b] * mem[n][d]
// v3: waves split N, not b. Wave wv handles rows nn === wv (mod 4) and
// accumulates ALL 32 b (acc[32][4] = 128 VGPRs, constant-indexed only).
// Every mem byte is loaded exactly once per split -- R1's layout had all
// 4 waves loading IDENTICAL addresses; MSHR-merge collapsed in-flight
// bytes to ~2.5 KB/CU = the measured 0.83 TB/s. Depth-4 named ring
// (affine, wave-uniform guards, no clamps) for ~3 KB in flight per wave.
// w broadcast from LDS (uniform address = conflict-free). Cross-wave
// reduce at the end via a 32 KB LDS buffer UNIONED with the w-tile.
__global__ __launch_bounds__(256, 2) void k_read(const float* __restrict__ mem,
                                                 const float* __restrict__ w,
                                                 float* __restrict__ partial,
                                                 int nPerS) {
    const int db   = blockIdx.x % 98;
    const int s    = blockIdx.x / 98;
    const int n0   = s * nPerS;
    const int lane = threadIdx.x & 63;
    const int wv   = threadIdx.x >> 6;          // 0..3 = n-parity
    const int d4   = db * 64 + lane;            // float4 column, < 6272

    const float4* M4 = (const float4*)mem;
    const float4* W4 = (const float4*)w;        // [n][8] float4

    __shared__ __align__(16) char smem[32768];  // union: wls (25.6KB) / red (32KB)
    float4* wls = (float4*)smem;                         // [RTILE][8]
    float4 (*red)[8][64] = (float4 (*)[8][64])smem;      // [wave][j][col]

    float acc[32][4];
#pragma unroll
    for (int i = 0; i < 32; ++i) {
        acc[i][0] = 0.f; acc[i][1] = 0.f; acc[i][2] = 0.f; acc[i][3] = 0.f;
    }

    for (int c0 = 0; c0 < nPerS; c0 += RTILE) { // nPerS is a multiple of 200
        __syncthreads();                         // prior tile done with wls
        for (int i = threadIdx.x; i < RTILE * 8; i += 256)
            wls[i] = W4[(size_t)(n0 + c0) * 8 + i];
        __syncthreads();

        const float4* mp = M4 + (size_t)(n0 + c0) * D4 + d4;
        // depth-4 ring: rows wv, wv+4, ..., wv+196 (50 rows/wave, exact)
        float4 mv0 = mp[(size_t)(wv)      * D4];
        float4 mv1 = mp[(size_t)(wv + 4)  * D4];
        float4 mv2 = mp[(size_t)(wv + 8)  * D4];
        float4 mv3 = mp[(size_t)(wv + 12) * D4];
        for (int nn = wv; nn < RTILE; nn += 4) {
            const float4 mc = mv0;
            mv0 = mv1; mv1 = mv2; mv2 = mv3;
            if (nn + 16 < RTILE)                 // wave-uniform, affine
                mv3 = mp[(size_t)(nn + 16) * D4];
#pragma unroll
            for (int q = 0; q < 8; ++q) {
                const float4 wq = wls[nn * 8 + q];   // LDS broadcast
                const int b0 = q * 4;
                acc[b0+0][0] += wq.x * mc.x; acc[b0+0][1] += wq.x * mc.y;
                acc[b0+0][2] += wq.x * mc.z; acc[b0+0][3] += wq.x * mc.w;
                acc[b0+1][0] += wq.y * mc.x; acc[b0+1][1] += wq.y * mc.y;
                acc[b0+1][2] += wq.y * mc.z; acc[b0+1][3] += wq.y * mc.w;
                acc[b0+2][0] += wq.z * mc.x; acc[b0+2][1] += wq.z * mc.y;
                acc[b0+2][2] += wq.z * mc.z; acc[b0+2][3] += wq.z * mc.w;
                acc[b0+3][0] += wq.w * mc.x; acc[b0+3][1] += wq.w * mc.y;
                acc[b0+3][2] += wq.w * mc.z; acc[b0+3][3] += wq.w * mc.w;
            }
        }
    }

    // cross-wave reduce: 4 passes of 8 b each through red[4][8][64]
    float4* P4 = (float4*)partial;
    const int col = threadIdx.x & 63;
    const int jj  = threadIdx.x >> 6;           // 0..3
#pragma unroll
    for (int p = 0; p < 4; ++p) {
        __syncthreads();                        // red buffer free (or wls done)
#pragma unroll
        for (int j = 0; j < 8; ++j)
            red[wv][j][lane] = make_float4(acc[p*8+j][0], acc[p*8+j][1],
                                           acc[p*8+j][2], acc[p*8+j][3]);
        __syncthreads();
#pragma unroll
        for (int h = 0; h < 2; ++h) {
            const int j = jj + h * 4;
            const float4 a = red[0][j][col], b = red[1][j][col];
            const float4 c = red[2][j][col], d = red[3][j][col];
            P4[(size_t)(s * B_KEYS + p * 8 + j) * D4 + db * 64 + col] =
                make_float4(a.x + b.x + c.x + d.x, a.y + b.y + c.y + d.y,
                            a.z + b.z + c.z + d.z, a.w + b.w + c.w + d.w);
        }
    }
}

__global__ __launch_bounds__(256) void k_finish(const float* __restrict__ partial,
                                                float* __restrict__ out, int ns) {
    const int i = blockIdx.x * 256 + threadIdx.x;   // float4 index, grid 784*256
    const float4* P4 = (const float4*)partial;
    float4 sum = P4[i];
    for (int s = 1; s < ns; ++s) {
        const float4 p = P4[(size_t)s * (B_KEYS * D4) + i];
        sum.x += p.x; sum.y += p.y; sum.z += p.z; sum.w += p.w;
    }
    ((float4*)out)[i] = sum;
}

extern "C" void kernel_launch(void* const* d_in, const int* in_sizes, int n_in,
                              void* d_out, int out_size, void* d_ws, size_t ws_size,
                              hipStream_t stream) {
    (void)in_sizes; (void)n_in; (void)out_size;
    const float* key = (const float*)d_in[0];
    const float* mem = (const float*)d_in[1];
    float* out = (float*)d_out;
    float* ws  = (float*)d_ws;

    short* keyb      = (short*)ws;      // 802816 shorts = 401408 floats
    float* dots_part = ws + 401408;     // 3136000 floats
    float* mn2_part  = ws + 3537408;    // 98000 floats
    float* dots      = ws + 3635408;    // 64000 floats
    float* mn2       = ws + 3699408;    // 2000 floats
    float* knorm     = ws + 3701408;    // 32 floats
    float* w         = ws + 3701440;    // 64000 floats (16B aligned)
    float* part      = ws + 3765440;    // ns * 802816 floats (16B aligned)

    // ns ladder keeps nPerS a multiple of RTILE=200: 10, 5, 2, 1
    int ns = 10;
    while (ns > 1 && (size_t)(3765440 + (size_t)ns * 802816) * 4 > ws_size)
        ns = (ns == 10) ? 5 : (ns == 5) ? 2 : 1;
    const int nPerS = N_MEM / ns;

    k_prep     <<<784, 256, 0, stream>>>(key, keyb);
    k_knorm    <<<B_KEYS, 256, 0, stream>>>(key, knorm);
    k_dots_mfma<<<125 * NSLICE, 64, 0, stream>>>(keyb, mem, dots_part, mn2_part);
    k_reduce   <<<250, 256, 0, stream>>>(dots_part, mn2_part, dots, mn2);
    k_softmax  <<<B_KEYS, 512, 0, stream>>>(knorm, dots, mn2, w);
    k_read     <<<98 * ns, 256, 0, stream>>>(mem, w, part, nPerS);
    k_finish   <<<784, 256, 0, stream>>>(part, out, ns);
}

// Round 9
// 373.182 us; speedup vs baseline: 1.0286x; 1.0286x over previous
//
#include <hip/hip_runtime.h>
#include <math.h>

// Problem constants
#define D_ELEMS 25088   // C*H*W = 512*7*7
#define D4      6272    // D_ELEMS / 4
#define N_MEM   2000
#define B_KEYS  32
#define PI_2F   1.570795f   // 3.14159 / 2, matches reference
#define EPSF    1e-8f
#define NSLICE  49          // k-slices for k_dots_mfma
#define KSLICE  512         // 25088 / 49
#define KSTEPS  16          // KSLICE / 32
#define MTILE   25          // mem rows staged per LDS tile in k_read

using short8 = __attribute__((ext_vector_type(8))) short;   // 8 bf16 A/B frag
using short4v = __attribute__((ext_vector_type(4))) short;
using f32x4  = __attribute__((ext_vector_type(4))) float;   // C/D frag

// ws layout (floats):
//   keyb (bf16 keys, as shorts)   : [0, 401408)
//   dots_part [49][2000][32]      : [401408, 3537408)
//   mn2_part  [49][2000]          : [3537408, 3635408)
//   dots      [2000][32]          : [3635408, 3699408)
//   mn2       [2000]              : [3699408, 3701408)
//   knorm     [32]                : [3701408, 3701440)
//   w         [2000][32]          : [3701440, 3765440)   (16B aligned)
//   partial [ns][32][25088]       : [3765440, +ns*802816) (16B aligned)

__device__ inline short f2bf(float x) {   // fp32 -> bf16 RNE (inputs finite)
    union { float f; unsigned u; } v; v.f = x;
    unsigned r = v.u + 0x7fffu + ((v.u >> 16) & 1u);
    return (short)(r >> 16);
}

// Convert keys fp32 -> bf16. 802816 elems, 4 per thread, grid 784*256.
__global__ __launch_bounds__(256) void k_prep(const float* __restrict__ key,
                                              short* __restrict__ keyb) {
    const int i = blockIdx.x * 256 + threadIdx.x;   // float4 index
    const float4 f = ((const float4*)key)[i];
    short4v s; s[0] = f2bf(f.x); s[1] = f2bf(f.y); s[2] = f2bf(f.z); s[3] = f2bf(f.w);
    ((short4v*)keyb)[i] = s;
}

// knorm[b] = max(||key[b]||, eps). 32 blocks x 256 threads, shuffle reduce.
__global__ __launch_bounds__(256) void k_knorm(const float* __restrict__ key,
                                               float* __restrict__ knorm) {
    const int b   = blockIdx.x;
    const int tid = threadIdx.x;
    const float4* K4 = (const float4*)(key + (size_t)b * D_ELEMS);
    float ks = 0.f;
    for (int i = tid; i < D4; i += 256) {
        const float4 f = K4[i];
        ks += f.x * f.x + f.y * f.y + f.z * f.z + f.w * f.w;
    }
#pragma unroll
    for (int o = 1; o < 64; o <<= 1) ks += __shfl_xor(ks, o, 64);
    __shared__ float sred[4];
    if ((tid & 63) == 0) sred[tid >> 6] = ks;
    __syncthreads();
    if (tid == 0)
        knorm[b] = fmaxf(sqrtf(sred[0] + sred[1] + sred[2] + sred[3]), EPSF);
}

// dots_part[s][n][b] = sum_{k in slice s} key[b][k]*mem[n][k]  (bf16 MFMA)
// mn2_part[s][n]     = sum_{k in slice s} mem[n][k]^2          (fp32)
// grid: 125 n-tiles x 49 slices = 6125 blocks of 1 wave (R1-exact).
__global__ __launch_bounds__(64) void k_dots_mfma(const short* __restrict__ keyb,
                                                  const float* __restrict__ mem,
                                                  float* __restrict__ dots_part,
                                                  float* __restrict__ mn2_part) {
    const int nt   = blockIdx.x / NSLICE;     // 0..124
    const int s    = blockIdx.x % NSLICE;     // 0..48
    const int n0   = nt * 16;
    const int lane = threadIdx.x;             // 0..63
    const int quad = lane >> 4;
    const int l16  = lane & 15;
    const int k0   = s * KSLICE + quad * 8;   // this lane's k base (floats)

    const short* a0p = keyb + (size_t)l16 * D_ELEMS + k0;          // keys 0..15
    const short* a1p = keyb + (size_t)(16 + l16) * D_ELEMS + k0;   // keys 16..31
    const float4* bp = (const float4*)(mem + (size_t)(n0 + l16) * D_ELEMS + k0);

    f32x4 acc0 = {0.f, 0.f, 0.f, 0.f};
    f32x4 acc1 = {0.f, 0.f, 0.f, 0.f};
    float msq = 0.f;

    // depth-1 prefetch: loads for step t+1 issue before the cvt+mfma of t
    short8 a0 = *(const short8*)a0p;
    short8 a1 = *(const short8*)a1p;
    float4 f0 = bp[0], f1 = bp[1];

    for (int t = 0; t < KSTEPS; ++t) {
        const short8 a0c = a0, a1c = a1;
        const float4 f0c = f0, f1c = f1;
        if (t + 1 < KSTEPS) {                 // wave-uniform branch
            a0 = *(const short8*)(a0p + (t + 1) * 32);
            a1 = *(const short8*)(a1p + (t + 1) * 32);
            f0 = bp[(t + 1) * 8];
            f1 = bp[(t + 1) * 8 + 1];
        }
        msq += f0c.x * f0c.x + f0c.y * f0c.y + f0c.z * f0c.z + f0c.w * f0c.w
             + f1c.x * f1c.x + f1c.y * f1c.y + f1c.z * f1c.z + f1c.w * f1c.w;
        short8 b;
        b[0] = f2bf(f0c.x); b[1] = f2bf(f0c.y); b[2] = f2bf(f0c.z); b[3] = f2bf(f0c.w);
        b[4] = f2bf(f1c.x); b[5] = f2bf(f1c.y); b[6] = f2bf(f1c.z); b[7] = f2bf(f1c.w);
        acc0 = __builtin_amdgcn_mfma_f32_16x16x32_bf16(a0c, b, acc0, 0, 0, 0);
        acc1 = __builtin_amdgcn_mfma_f32_16x16x32_bf16(a1c, b, acc1, 0, 0, 0);
    }

    // D[row=quad*4+r][col=l16]; row = key index (per m-half), col = n index
    float* dp = dots_part + (size_t)(s * N_MEM + n0 + l16) * B_KEYS;
#pragma unroll
    for (int r = 0; r < 4; ++r) {
        dp[quad * 4 + r]      = acc0[r];
        dp[16 + quad * 4 + r] = acc1[r];
    }

    // reduce msq across the 4 quads of each n-row (lanes l16, l16+16, ...)
    msq += __shfl_xor(msq, 16, 64);
    msq += __shfl_xor(msq, 32, 64);
    if (lane < 16) mn2_part[s * N_MEM + n0 + lane] = msq;
}

// Collapse the 49 slice partials: dots[n][b], mn2[n]. Coalesced. grid 250.
__global__ __launch_bounds__(256) void k_reduce(const float* __restrict__ dots_part,
                                                const float* __restrict__ mn2_part,
                                                float* __restrict__ dots,
                                                float* __restrict__ mn2) {
    const int gid = blockIdx.x * 256 + threadIdx.x;   // 0..63999
    float ds = 0.f;
#pragma unroll
    for (int s = 0; s < NSLICE; ++s) ds += dots_part[s * (N_MEM * B_KEYS) + gid];
    dots[gid] = ds;
    if (gid < N_MEM) {
        float ms = 0.f;
#pragma unroll
        for (int s = 0; s < NSLICE; ++s) ms += mn2_part[s * N_MEM + gid];
        mn2[gid] = ms;
    }
}

// per-b: cos -> tan -> softmax over n -> w. knorm precomputed by k_knorm.
__global__ __launch_bounds__(512) void k_softmax(const float* __restrict__ knormArr,
                                                 const float* __restrict__ dots,
                                                 const float* __restrict__ mn2,
                                                 float* __restrict__ w) {
    const int b   = blockIdx.x;
    const int tid = threadIdx.x;
    __shared__ float sred[512];
    __shared__ float xbuf[N_MEM];
    const float knorm = knormArr[b];

    float mx = -1e30f;
    for (int n = tid; n < N_MEM; n += 512) {
        const float mn = fmaxf(sqrtf(mn2[n]), EPSF);
        const float x  = __tanf((dots[n * B_KEYS + b] / (knorm * mn)) * PI_2F);
        xbuf[n] = x;
        mx = fmaxf(mx, x);
    }
    sred[tid] = mx;
    __syncthreads();
    for (int o = 256; o; o >>= 1) {
        if (tid < o) sred[tid] = fmaxf(sred[tid], sred[tid + o]);
        __syncthreads();
    }
    mx = sred[0];
    __syncthreads();

    float sm = 0.f;
    for (int n = tid; n < N_MEM; n += 512) {   // cache exp in xbuf (own slots)
        const float e = __expf(xbuf[n] - mx);
        xbuf[n] = e;
        sm += e;
    }
    sred[tid] = sm;
    __syncthreads();
    for (int o = 256; o; o >>= 1) {
        if (tid < o) sred[tid] += sred[tid + o];
        __syncthreads();
    }
    const float inv = 1.f / sred[0];

    for (int n = tid; n < N_MEM; n += 512)
        w[n * B_KEYS + b] = xbuf[n] * inv;
}

// partial[s][b][d] = sum_{n in split s} w[n][b] * mem[n][d]
// v4: LDS-STAGED mem rows. R4 counters proved b-split waves reading
// identical addresses MSHR-merge to ~2.4 KB/CU unique in flight (830 GB/s,
// all pipes idle); wave-level n/d splits fix redundancy but need
// acc[32][4]=128 VGPR (occupancy halves -- R7/R8 nulls). Staging breaks
// the tension: 256 threads cooperatively load each 25-row x 64-f4 tile
// ONCE (7 independent affine loads/thread = ~24 KB/block in flight, no
// manual ring), then 4 waves consume from LDS (b-octet each, acc[8][4]=32
// VGPR, (256,4)=16 waves/CU). mls reads are contiguous-b128 conflict-free;
// w reads are uniform-address broadcasts. 4 blocks/CU overlap barriers.
__global__ __launch_bounds__(256, 4) void k_read(const float* __restrict__ mem,
                                                 const float* __restrict__ w,
                                                 float* __restrict__ partial,
                                                 int nPerS) {
    const int db   = blockIdx.x % 98;
    const int s    = blockIdx.x / 98;
    const int n0   = s * nPerS;
    const int lane = threadIdx.x & 63;
    const int wv   = threadIdx.x >> 6;          // b-octet: b = wv*8 .. wv*8+7
    const int d4   = db * 64 + lane;            // float4 column, < 6272

    const float4* M4 = (const float4*)mem;
    const float4* W4 = (const float4*)w;        // [n][8] float4

    __shared__ float4 mls[MTILE * 64];          // 25 rows x 64 f4 = 25.6 KB
    __shared__ float4 wls[MTILE * 8];           // 25 rows x 32 b  =  3.2 KB

    float acc[8][4];
#pragma unroll
    for (int i = 0; i < 8; ++i) {
        acc[i][0] = 0.f; acc[i][1] = 0.f; acc[i][2] = 0.f; acc[i][3] = 0.f;
    }

    for (int c0 = 0; c0 < nPerS; c0 += MTILE) { // nPerS is a multiple of 25
        __syncthreads();                        // prior tile fully consumed
        // stage 25 mem rows (1600 f4): i -> (row i>>6, col i&63), coalesced
        for (int i = threadIdx.x; i < MTILE * 64; i += 256)
            mls[i] = M4[(size_t)(n0 + c0 + (i >> 6)) * D4 + db * 64 + (i & 63)];
        if (threadIdx.x < MTILE * 8)
            wls[threadIdx.x] = W4[(size_t)(n0 + c0) * 8 + threadIdx.x];
        __syncthreads();

#pragma unroll 5
        for (int r = 0; r < MTILE; ++r) {
            const float4 mc = mls[r * 64 + lane];        // b128, conflict-free
            const float4 wa = wls[r * 8 + wv * 2];       // broadcast
            const float4 wb = wls[r * 8 + wv * 2 + 1];   // broadcast
            const float wvv[8] = {wa.x, wa.y, wa.z, wa.w, wb.x, wb.y, wb.z, wb.w};
#pragma unroll
            for (int i = 0; i < 8; ++i) {
                acc[i][0] += wvv[i] * mc.x;
                acc[i][1] += wvv[i] * mc.y;
                acc[i][2] += wvv[i] * mc.z;
                acc[i][3] += wvv[i] * mc.w;
            }
        }
    }

    float4* P4 = (float4*)partial;
#pragma unroll
    for (int i = 0; i < 8; ++i)
        P4[(size_t)(s * B_KEYS + wv * 8 + i) * D4 + d4] =
            make_float4(acc[i][0], acc[i][1], acc[i][2], acc[i][3]);
}

__global__ __launch_bounds__(256) void k_finish(const float* __restrict__ partial,
                                                float* __restrict__ out, int ns) {
    const int i = blockIdx.x * 256 + threadIdx.x;   // float4 index, grid 784*256
    const float4* P4 = (const float4*)partial;
    float4 sum = P4[i];
    for (int s = 1; s < ns; ++s) {
        const float4 p = P4[(size_t)s * (B_KEYS * D4) + i];
        sum.x += p.x; sum.y += p.y; sum.z += p.z; sum.w += p.w;
    }
    ((float4*)out)[i] = sum;
}

extern "C" void kernel_launch(void* const* d_in, const int* in_sizes, int n_in,
                              void* d_out, int out_size, void* d_ws, size_t ws_size,
                              hipStream_t stream) {
    (void)in_sizes; (void)n_in; (void)out_size;
    const float* key = (const float*)d_in[0];
    const float* mem = (const float*)d_in[1];
    float* out = (float*)d_out;
    float* ws  = (float*)d_ws;

    short* keyb      = (short*)ws;      // 802816 shorts = 401408 floats
    float* dots_part = ws + 401408;     // 3136000 floats
    float* mn2_part  = ws + 3537408;    // 98000 floats
    float* dots      = ws + 3635408;    // 64000 floats
    float* mn2       = ws + 3699408;    // 2000 floats
    float* knorm     = ws + 3701408;    // 32 floats
    float* w         = ws + 3701440;    // 64000 floats (16B aligned)
    float* part      = ws + 3765440;    // ns * 802816 floats (16B aligned)

    // ns candidates: 8, 4, 2, 1 (every nPerS is a multiple of MTILE=25)
    int ns = 8;
    while (ns > 1 && (size_t)(3765440 + (size_t)ns * 802816) * 4 > ws_size) ns >>= 1;
    const int nPerS = N_MEM / ns;

    k_prep     <<<784, 256, 0, stream>>>(key, keyb);
    k_knorm    <<<B_KEYS, 256, 0, stream>>>(key, knorm);
    k_dots_mfma<<<125 * NSLICE, 64, 0, stream>>>(keyb, mem, dots_part, mn2_part);
    k_reduce   <<<250, 256, 0, stream>>>(dots_part, mn2_part, dots, mn2);
    k_softmax  <<<B_KEYS, 512, 0, stream>>>(knorm, dots, mn2, w);
    k_read     <<<98 * ns, 256, 0, stream>>>(mem, w, part, nPerS);
    k_finish   <<<784, 256, 0, stream>>>(part, out, ns);
}